// Round 2
// baseline (1356.527 us; speedup 1.0000x reference)
//
#include <hip/hip_runtime.h>

// HGCN on MI355X. logmap0(expmap0(v)) == v here, so the model reduces to:
//   t1 = sigmoid(segmean(feat@W1+b1)); t2 = sigmoid(segmean(t1@W2+b2))
//   out = relu(t2@W3+b3)@W4 + b4     (segmean commutes with the linear map;
//   deg-0 nodes: segmean = 0 -> value 0.5 exactly, handled via dz check)
// R1-R13: see session journal (atomic wall -> CSR; coarse buckets; bf16
//   gather rows; frag-packed weight image; wave-local zero-barrier MLP).
// R14: baseline re-anchor, 229.4us. Counters: aggep3 59us @ MfmaUtil 2%,
//   VALUBusy 26%, HBM 21%, occ 31% -> gathers latency-bound; csr_fine +
//   part_prep ~110us (csr_fine: 196 blocks = 0.77/CU serial latency).
// R15: TILE-GRANULAR SORT. Gather tiles are 64 nodes, so edges only need
//   sorting to tile granularity -> csr_fine ELIMINATED. part_prep radix
//   scatters straight into 1563 per-tile arenas (7-bins/thread LDS scan).
//   Gather streams the unsorted tile list divergence-free (8 lanes/edge,
//   4-deep batch) into a bank-padded LDS fp32 accumulator via ds_add_f32;
//   degree counted in LDS (dz check preserved); wave-local pack -> MFMA
//   unchanged. Predicted 229 -> ~160us.

constexpr int TSHIFT = 6;               // 64-node tiles == gather tile
constexpr int EPB    = 4096;            // edges per partition block
constexpr int EPT    = EPB / 256;
constexpr int CAP    = 2048;            // arena capacity per tile (mean 1024)
constexpr int BPT    = 7;               // bins per thread in partition scan
constexpr int BINMAX = 256 * BPT;       // 1792 >= NBUCK=1563
constexpr int ASTR   = 68;              // AccF row stride (floats), bank pad

// frag-packed bf16 weight image (shorts). Fragment = 16 lanes x 8 shorts =
// 128 shorts; flat idx = (((c*KK + kk)*4 + quad)*16 + m)*8 + j.
constexpr int W1F_OFF = 0;              // 4x2x4 frags  = 4096 shorts
constexpr int W2F_OFF = 4096;           // 4096
constexpr int W3F_OFF = 8192;           // 8x2x4 frags  = 8192
constexpr int W4F_OFF = 16384;          // 3x4x4 frags  = 6144 (cols padded 48)
constexpr int WIMG_TOT = 22528;

typedef __attribute__((ext_vector_type(8))) short short8;   // 8 bf16
typedef __attribute__((ext_vector_type(4))) float floatx4;  // MFMA acc

__device__ __forceinline__ float sigmoidf(float x) {
    return 1.0f / (1.0f + __expf(-x));
}
__device__ __forceinline__ unsigned short f2bf(float f) {   // RNE f32->bf16
    unsigned int u = __float_as_uint(f);
    u = (u + 0x7FFFu + ((u >> 16) & 1u)) >> 16;
    return (unsigned short)u;
}

// ---------------- tile partition + one-time prep (merged launch) -----------
// Blocks [0,gP): radix-partition edges into per-TILE arena regions.
// Blocks [gP,..): feat fp32->bf16 cast + frag-packed weight image build.
__global__ __launch_bounds__(256) void part_prep_k(
    const int* __restrict__ src, const int* __restrict__ dst,
    int* __restrict__ ccur, int* __restrict__ arena, int E, int NBUCK, int gP,
    const float* __restrict__ feat, unsigned short* __restrict__ featbf,
    const float* __restrict__ W1, const float* __restrict__ W2,
    const float* __restrict__ W3, const float* __restrict__ W4,
    unsigned short* __restrict__ img, int n8)
{
    __shared__ int  histA[BINMAX];          // counts -> lcur (in place)
    __shared__ int  deltaA[BINMAX];         // global_base - block_excl
    __shared__ int  part[256];
    __shared__ int  stage[EPB];
    __shared__ unsigned short stageS[EPB];  // tile id per staged edge

    const int tid = threadIdx.x;

    if ((int)blockIdx.x >= gP) {
        // ---- prep path ----
        int i = ((int)blockIdx.x - gP) * 256 + tid;
        if (i < n8) {
            const float4* p = (const float4*)feat + (size_t)i * 2;
            float4 a = p[0], b = p[1];
            uint4 o;
            o.x = (unsigned)f2bf(a.x) | ((unsigned)f2bf(a.y) << 16);
            o.y = (unsigned)f2bf(a.z) | ((unsigned)f2bf(a.w) << 16);
            o.z = (unsigned)f2bf(b.x) | ((unsigned)f2bf(b.y) << 16);
            o.w = (unsigned)f2bf(b.z) | ((unsigned)f2bf(b.w) << 16);
            ((uint4*)featbf)[i] = o;
            return;
        }
        int t = i - n8;
        if (t >= WIMG_TOT) return;
        float v = 0.f;
        int s = t;
        if (s < W2F_OFF) {                       // W1 [64x64]
            int j = s & 7, m = (s >> 3) & 15, q = (s >> 7) & 3, kk = (s >> 9) & 1, c = s >> 10;
            v = W1[(kk * 32 + q * 8 + j) * 64 + c * 16 + m];
        } else if (s < W3F_OFF) {                // W2 [64x64]
            s -= W2F_OFF;
            int j = s & 7, m = (s >> 3) & 15, q = (s >> 7) & 3, kk = (s >> 9) & 1, c = s >> 10;
            v = W2[(kk * 32 + q * 8 + j) * 64 + c * 16 + m];
        } else if (s < W4F_OFF) {                // W3 [64x128]
            s -= W3F_OFF;
            int j = s & 7, m = (s >> 3) & 15, q = (s >> 7) & 3, kk = (s >> 9) & 1, c = s >> 10;
            v = W3[(kk * 32 + q * 8 + j) * 128 + c * 16 + m];
        } else {                                 // W4 [128x40], cols padded 48
            s -= W4F_OFF;
            int j = s & 7, m = (s >> 3) & 15, q = (s >> 7) & 3, kk = (s >> 9) & 3, c = s >> 11;
            int n = c * 16 + m;
            if (n < 40) v = W4[(kk * 32 + q * 8 + j) * 40 + n];
        }
        img[t] = f2bf(v);
        return;
    }

    // ---- partition path ----
    const int e0  = blockIdx.x * EPB;
    const int ec  = min(EPB, E - e0);

    int pk[EPT], bk[EPT];
    for (int k = tid; k < BINMAX; k += 256) histA[k] = 0;
    __syncthreads();
    #pragma unroll
    for (int j = 0; j < EPT; j++) {
        int idx = tid + j * 256;
        if (idx < ec) {
            int s = src[e0 + idx];
            int d = dst[e0 + idx];
            bk[j] = d >> TSHIFT;                 // tile id (0..1562)
            pk[j] = s | ((d & 63) << 17);        // src 17b | fine-node 6b
            atomicAdd(&histA[bk[j]], 1);
        } else bk[j] = -1;
    }
    __syncthreads();
    // 7-bins-per-thread local sums -> 256-wide scan -> per-bin offsets
    int loc[BPT];
    int ssum = 0;
    #pragma unroll
    for (int k = 0; k < BPT; k++) {
        loc[k] = ssum;
        ssum += histA[tid * BPT + k];
    }
    part[tid] = ssum;
    __syncthreads();
    for (int dd = 1; dd < 256; dd <<= 1) {
        int v = 0;
        if (tid >= dd) v = part[tid - dd];
        __syncthreads();
        if (tid >= dd) part[tid] += v;
        __syncthreads();
    }
    const int base0 = part[tid] - ssum;
    #pragma unroll
    for (int k = 0; k < BPT; k++) {
        int b  = tid * BPT + k;
        int h  = histA[b];
        int ex = base0 + loc[k];
        int gb = 0;
        if (b < NBUCK && h > 0) gb = atomicAdd(ccur + b, h);
        deltaA[b] = gb - ex;
        histA[b]  = ex;                          // becomes lcur
    }
    __syncthreads();
    #pragma unroll
    for (int j = 0; j < EPT; j++) {
        if (bk[j] >= 0) {
            int l = atomicAdd(&histA[bk[j]], 1);
            stage[l]  = pk[j];
            stageS[l] = (unsigned short)bk[j];
        }
    }
    __syncthreads();
    for (int i = tid; i < ec; i += 256) {
        int b = stageS[i];
        arena[(size_t)b * CAP + i + deltaA[b]] = stage[i];
    }
}

// ---------------- divergence-free tile gather into LDS fp32 accumulator ----
// Each 8-lane group handles one edge/iter (full 128B row, coalesced), 4-deep
// batched; ds_add_f32 into bank-padded AccF[64][68]; degree counted in LDS.
// Then wave-local mean + bf16 pack of OWN rows into Agg (MFMA A layout).
__device__ __forceinline__ void ds_acc8(float* A, uint4 v) {
    atomicAdd(A + 0, __uint_as_float(v.x << 16));
    atomicAdd(A + 1, __uint_as_float(v.x & 0xFFFF0000u));
    atomicAdd(A + 2, __uint_as_float(v.y << 16));
    atomicAdd(A + 3, __uint_as_float(v.y & 0xFFFF0000u));
    atomicAdd(A + 4, __uint_as_float(v.z << 16));
    atomicAdd(A + 5, __uint_as_float(v.z & 0xFFFF0000u));
    atomicAdd(A + 6, __uint_as_float(v.w << 16));
    atomicAdd(A + 7, __uint_as_float(v.w & 0xFFFF0000u));
}

__device__ __forceinline__ void gather_tile_accum(
    const unsigned short* __restrict__ h, const int* __restrict__ ebase,
    int ec, float* AccF, int* degL, unsigned short* Agg, int tid)
{
    for (int k = tid; k < 64 * ASTR; k += 256) AccF[k] = 0.f;
    if (tid < 64) degL[tid] = 0;
    __syncthreads();

    const int l8 = tid & 7, q = l8 * 8;
    int i = tid >> 3;
    for (; i + 96 < ec; i += 128) {              // 4 edges in flight / lane
        int ea = ebase[i], eb = ebase[i + 32], ecx = ebase[i + 64], ed = ebase[i + 96];
        uint4 va = *(const uint4*)(h + (size_t)(ea & 0x1FFFF) * 64 + q);
        uint4 vb = *(const uint4*)(h + (size_t)(eb & 0x1FFFF) * 64 + q);
        uint4 vc = *(const uint4*)(h + (size_t)(ecx & 0x1FFFF) * 64 + q);
        uint4 vd = *(const uint4*)(h + (size_t)(ed & 0x1FFFF) * 64 + q);
        int fa = (ea >> 17) & 63, fb = (eb >> 17) & 63;
        int fc = (ecx >> 17) & 63, fd = (ed >> 17) & 63;
        ds_acc8(AccF + fa * ASTR + q, va);
        ds_acc8(AccF + fb * ASTR + q, vb);
        ds_acc8(AccF + fc * ASTR + q, vc);
        ds_acc8(AccF + fd * ASTR + q, vd);
        if (l8 == 0) {
            atomicAdd(&degL[fa], 1); atomicAdd(&degL[fb], 1);
            atomicAdd(&degL[fc], 1); atomicAdd(&degL[fd], 1);
        }
    }
    for (; i < ec; i += 32) {
        int ea = ebase[i];
        uint4 va = *(const uint4*)(h + (size_t)(ea & 0x1FFFF) * 64 + q);
        int fa = (ea >> 17) & 63;
        ds_acc8(AccF + fa * ASTR + q, va);
        if (l8 == 0) atomicAdd(&degL[fa], 1);
    }
    __syncthreads();

    // wave-local pack: thread (w,lane) -> row = tid>>2 in [16w,16w+16)
    const int row = tid >> 2, c0 = (tid & 3) * 16;
    const float inv = __builtin_amdgcn_rcpf((float)max(degL[row], 1));
    const float4* Ar = (const float4*)(AccF + row * ASTR + c0);
    float4 x0 = Ar[0], x1 = Ar[1], x2 = Ar[2], x3 = Ar[3];
    uint4 o0, o1;
    o0.x = (unsigned)f2bf(x0.x * inv) | ((unsigned)f2bf(x0.y * inv) << 16);
    o0.y = (unsigned)f2bf(x0.z * inv) | ((unsigned)f2bf(x0.w * inv) << 16);
    o0.z = (unsigned)f2bf(x1.x * inv) | ((unsigned)f2bf(x1.y * inv) << 16);
    o0.w = (unsigned)f2bf(x1.z * inv) | ((unsigned)f2bf(x1.w * inv) << 16);
    o1.x = (unsigned)f2bf(x2.x * inv) | ((unsigned)f2bf(x2.y * inv) << 16);
    o1.y = (unsigned)f2bf(x2.z * inv) | ((unsigned)f2bf(x2.w * inv) << 16);
    o1.z = (unsigned)f2bf(x3.x * inv) | ((unsigned)f2bf(x3.y * inv) << 16);
    o1.w = (unsigned)f2bf(x3.z * inv) | ((unsigned)f2bf(x3.w * inv) << 16);
    *(uint4*)(Agg + row * 72 + c0)     = o0;
    *(uint4*)(Agg + row * 72 + c0 + 8) = o1;
}

// ---------------- fused gather + GEMM1 + sigmoid -> t1 ---------------------
__global__ __launch_bounds__(256) void aggemm1_k(
    const unsigned short* __restrict__ featbf, const int* __restrict__ ccur,
    const int* __restrict__ arena, const unsigned short* __restrict__ img,
    const float* __restrict__ bias, unsigned short* __restrict__ t1, int N)
{
    __shared__ alignas(16) unsigned char SMEM[64 * ASTR * 4 + 9216 + 256];
    float*          AccF = (float*)SMEM;                       // 17408 B
    unsigned short* Agg  = (unsigned short*)(SMEM + 64 * ASTR * 4);
    int*            degL = (int*)(SMEM + 64 * ASTR * 4 + 9216);

    const int tid = threadIdx.x;
    const int tile = blockIdx.x;
    const int rowB = tile * 64;
    const int w = tid >> 6, lane = tid & 63;
    const int m = lane & 15, quad = lane >> 4;
    const int row0 = rowB + w * 16;

    gather_tile_accum(featbf, arena + (size_t)tile * CAP, ccur[tile],
                      AccF, degL, Agg, tid);

    const short8* Wf = (const short8*)(img + W1F_OFF);
    floatx4 acc[4];
    #pragma unroll
    for (int c = 0; c < 4; c++) acc[c] = (floatx4){0.f, 0.f, 0.f, 0.f};
    #pragma unroll
    for (int kk = 0; kk < 2; kk++) {
        short8 a = *(const short8*)(Agg + (w * 16 + m) * 72 + kk * 32 + quad * 8);
        #pragma unroll
        for (int c = 0; c < 4; c++) {
            short8 b = Wf[((c * 2 + kk) * 4 + quad) * 16 + m];
            acc[c] = __builtin_amdgcn_mfma_f32_16x16x32_bf16(a, b, acc[c], 0, 0, 0);
        }
    }
    bool dzr[4];
    int rows[4];
    #pragma unroll
    for (int r = 0; r < 4; r++) {
        rows[r] = row0 + quad * 4 + r;
        dzr[r] = (degL[w * 16 + quad * 4 + r] == 0);
    }
    #pragma unroll
    for (int c = 0; c < 4; c++) {
        int col = c * 16 + m;
        float bv = bias[col];
        #pragma unroll
        for (int r = 0; r < 4; r++) {
            if (rows[r] < N) {
                float v = dzr[r] ? 0.5f : sigmoidf(acc[c][r] + bv);
                t1[(size_t)rows[r] * 64 + col] = f2bf(v);
            }
        }
    }
}

// ---------------- fused gather + triple-GEMM -> out ------------------------
// LDS: AccF (17.4KB, reused as T2 after pack) | Agg/H3h (9.2KB) | degL.
// Barrier after pack isolates T2 writes from other waves' AccF reads.
__global__ __launch_bounds__(256) void aggep3_k(
    const unsigned short* __restrict__ t1, const int* __restrict__ ccur,
    const int* __restrict__ arena, const unsigned short* __restrict__ img,
    const float* __restrict__ b2, const float* __restrict__ b3,
    const float* __restrict__ b4, float* __restrict__ out, int N)
{
    __shared__ alignas(16) unsigned char SMEM[64 * ASTR * 4 + 9216 + 256];
    float*          AccF = (float*)SMEM;
    unsigned short* T2   = (unsigned short*)SMEM;              // aliases AccF
    unsigned short* Agg  = (unsigned short*)(SMEM + 64 * ASTR * 4);
    unsigned short* H3h  = Agg;                                // aliases Agg
    int*            degL = (int*)(SMEM + 64 * ASTR * 4 + 9216);

    const int tid = threadIdx.x;
    const int tile = blockIdx.x;
    const int rowB = tile * 64;
    const int w = tid >> 6, lane = tid & 63;
    const int m = lane & 15, quad = lane >> 4;
    const int row0 = rowB + w * 16;

    gather_tile_accum(t1, arena + (size_t)tile * CAP, ccur[tile],
                      AccF, degL, Agg, tid);
    __syncthreads();    // all AccF reads done before T2 (alias) writes

    // ---- phase 0: T2 = sigmoid(Agg @ W2 + b2) ----
    {
        const short8* Wf = (const short8*)(img + W2F_OFF);
        floatx4 acc[4];
        #pragma unroll
        for (int c = 0; c < 4; c++) acc[c] = (floatx4){0.f, 0.f, 0.f, 0.f};
        #pragma unroll
        for (int kk = 0; kk < 2; kk++) {
            short8 a = *(const short8*)(Agg + (w * 16 + m) * 72 + kk * 32 + quad * 8);
            #pragma unroll
            for (int c = 0; c < 4; c++) {
                short8 b = Wf[((c * 2 + kk) * 4 + quad) * 16 + m];
                acc[c] = __builtin_amdgcn_mfma_f32_16x16x32_bf16(a, b, acc[c], 0, 0, 0);
            }
        }
        bool dzr[4];
        #pragma unroll
        for (int r = 0; r < 4; r++)
            dzr[r] = (degL[w * 16 + quad * 4 + r] == 0);
        #pragma unroll
        for (int c = 0; c < 4; c++) {
            int col = c * 16 + m;
            float bv = b2[col];
            #pragma unroll
            for (int r = 0; r < 4; r++) {
                int rl = w * 16 + quad * 4 + r;
                float v = dzr[r] ? 0.5f : sigmoidf(acc[c][r] + bv);
                T2[rl * 72 + col] = f2bf(v);
            }
        }
    }

    // ---- phases 1&2 split-K: per half, H3h = relu(T2@W3half+b3half),
    //      then acc2 += H3h @ W4[khalf] ----
    floatx4 acc2[3];
    #pragma unroll
    for (int c = 0; c < 3; c++) acc2[c] = (floatx4){0.f, 0.f, 0.f, 0.f};
    const short8* Wf3 = (const short8*)(img + W3F_OFF);
    const short8* Wf4 = (const short8*)(img + W4F_OFF);

    #pragma unroll
    for (int half = 0; half < 2; half++) {
        floatx4 acc[4];
        #pragma unroll
        for (int c = 0; c < 4; c++) acc[c] = (floatx4){0.f, 0.f, 0.f, 0.f};
        #pragma unroll
        for (int kk = 0; kk < 2; kk++) {
            short8 a = *(const short8*)(T2 + (w * 16 + m) * 72 + kk * 32 + quad * 8);
            #pragma unroll
            for (int c = 0; c < 4; c++) {
                short8 b = Wf3[(((half * 4 + c) * 2 + kk) * 4 + quad) * 16 + m];
                acc[c] = __builtin_amdgcn_mfma_f32_16x16x32_bf16(a, b, acc[c], 0, 0, 0);
            }
        }
        #pragma unroll
        for (int c = 0; c < 4; c++) {
            int col = c * 16 + m;
            float bv = b3[half * 64 + col];
            #pragma unroll
            for (int r = 0; r < 4; r++) {
                int rl = w * 16 + quad * 4 + r;
                H3h[rl * 72 + col] = f2bf(fmaxf(acc[c][r] + bv, 0.f));
            }
        }
        #pragma unroll
        for (int kk2 = 0; kk2 < 2; kk2++) {
            short8 a = *(const short8*)(H3h + (w * 16 + m) * 72 + kk2 * 32 + quad * 8);
            #pragma unroll
            for (int c = 0; c < 3; c++) {
                short8 b = Wf4[((c * 4 + half * 2 + kk2) * 4 + quad) * 16 + m];
                acc2[c] = __builtin_amdgcn_mfma_f32_16x16x32_bf16(a, b, acc2[c], 0, 0, 0);
            }
        }
    }

    // ---- store out = acc2 + b4 ----
    #pragma unroll
    for (int c = 0; c < 3; c++) {
        int col = c * 16 + m;
        if (col < 40) {
            float bv = b4[col];
            #pragma unroll
            for (int r = 0; r < 4; r++) {
                int row = row0 + quad * 4 + r;
                if (row < N) out[(size_t)row * 40 + col] = acc2[c][r] + bv;
            }
        }
    }
}

extern "C" void kernel_launch(void* const* d_in, const int* in_sizes, int n_in,
                              void* d_out, int out_size, void* d_ws, size_t ws_size,
                              hipStream_t stream)
{
    const float* feat = (const float*)d_in[0];
    const int*   eidx = (const int*)d_in[1];
    const float* W1 = (const float*)d_in[2];
    const float* b1 = (const float*)d_in[3];
    const float* W2 = (const float*)d_in[4];
    const float* b2 = (const float*)d_in[5];
    const float* W3 = (const float*)d_in[6];
    const float* b3 = (const float*)d_in[7];
    const float* W4 = (const float*)d_in[8];
    const float* b4 = (const float*)d_in[9];

    const int N = in_sizes[0] / 64;
    const int E = in_sizes[1] / 2;
    const int* src = eidx;
    const int* dst = eidx + E;

    const int NBUCK = (N + 63) >> TSHIFT;          // 1563 tiles

    unsigned short* featbf = (unsigned short*)d_ws;            // N*64 bf16
    unsigned short* t1     = featbf + (size_t)N * 64;          // N*64 bf16
    unsigned short* img    = t1     + (size_t)N * 64;          // WIMG_TOT
    int*   ccur  = (int*)(img + WIMG_TOT);                     // NBUCK
    int*   arena = ccur + NBUCK;                               // NBUCK*CAP
    float* out   = (float*)d_out;

    hipMemsetAsync(ccur, 0, (size_t)NBUCK * sizeof(int), stream);

    const dim3 blk(256);
    const int gP  = (E + EPB - 1) / EPB;
    const int g64 = (N + 63) / 64;                 // == NBUCK
    const int n8  = N * 64 / 8;
    const int gPC = (n8 + WIMG_TOT + 255) / 256;

    // tile-granular partition + prep (merged); csr_fine eliminated (R15)
    part_prep_k<<<gP + gPC, blk, 0, stream>>>(src, dst, ccur, arena, E, NBUCK,
                                              gP, feat, featbf, W1, W2, W3, W4,
                                              img, n8);

    // t1 = sigmoid(mean(featbf[src]) @ W1 + b1)
    aggemm1_k<<<g64, blk, 0, stream>>>(featbf, ccur, arena, img, b1, t1, N);
    // out = relu(sigmoid(mean(t1[src])@W2+b2)@W3+b3)@W4 + b4
    aggep3_k<<<g64, blk, 0, stream>>>(t1, ccur, arena, img, b2, b3, b4, out, N);
}

// Round 3
// 240.485 us; speedup vs baseline: 5.6408x; 5.6408x over previous
//
#include <hip/hip_runtime.h>

// HGCN on MI355X. logmap0(expmap0(v)) == v here, so the model reduces to:
//   t1 = sigmoid(segmean(feat@W1+b1)); t2 = sigmoid(segmean(t1@W2+b2))
//   out = relu(t2@W3+b3)@W4 + b4     (segmean commutes with the linear map;
//   deg-0 nodes: segmean = 0 -> value 0.5 exactly, handled via dz check)
// R1-R13: see session journal (atomic wall -> CSR; coarse buckets; bf16
//   gather rows; frag-packed weight image; wave-local zero-barrier MLP).
// R14: baseline re-anchor, 229.4us. aggep3 59us @ MfmaUtil 2%, VALUBusy 26%,
//   HBM 21% -> gathers latency-bound; part_prep+csr_fine ~110us.
// R15: FAILED (1356us). LDS float atomicAdd lowers to a CAS loop (safe-FP
//   default), not ds_add_f32 -> 102M CAS round-trips/layer, VALUBusy 1.8%.
//   Lesson: int LDS atomics are native, float are not.
// R16: keep tile-granular partition (csr_fine still eliminated), restore the
//   PROVEN register gather; do the fine sort IN-BLOCK: 64-bin LDS int
//   histogram + 64-lane shuffle scan + LDS scatter of src ids (8KB), then
//   R13-style wave-local register gather reads src ids from LDS. sortedE
//   aliases T2 in aggep3 (one extra barrier). 19.2KB LDS -> 8 blocks/CU.
//   Predicted ~175-190us.

constexpr int TSHIFT = 6;               // 64-node tiles == gather tile
constexpr int EPB    = 4096;            // edges per partition block
constexpr int EPT    = EPB / 256;
constexpr int CAP    = 2048;            // arena capacity per tile (mean 1024)
constexpr int BPT    = 7;               // bins per thread in partition scan
constexpr int BINMAX = 256 * BPT;       // 1792 >= NBUCK=1563

// frag-packed bf16 weight image (shorts). Fragment = 16 lanes x 8 shorts =
// 128 shorts; flat idx = (((c*KK + kk)*4 + quad)*16 + m)*8 + j.
constexpr int W1F_OFF = 0;              // 4x2x4 frags  = 4096 shorts
constexpr int W2F_OFF = 4096;           // 4096
constexpr int W3F_OFF = 8192;           // 8x2x4 frags  = 8192
constexpr int W4F_OFF = 16384;          // 3x4x4 frags  = 6144 (cols padded 48)
constexpr int WIMG_TOT = 22528;

// gather-kernel LDS layout (bytes):
//   [0,9216)      sortedE (<=2304 ints)  | aggep3: T2[64x72] after barrier
//   [9216,18432)  Agg[64x72]             | aggep3: H3h alias
//   [18432,18688) cnt[64]   [18688,18944) beg[64]   [18944,19200) cur[64]
constexpr int SMEM_BYTES = 19200;

typedef __attribute__((ext_vector_type(8))) short short8;   // 8 bf16
typedef __attribute__((ext_vector_type(4))) float floatx4;  // MFMA acc

__device__ __forceinline__ float sigmoidf(float x) {
    return 1.0f / (1.0f + __expf(-x));
}
__device__ __forceinline__ unsigned short f2bf(float f) {   // RNE f32->bf16
    unsigned int u = __float_as_uint(f);
    u = (u + 0x7FFFu + ((u >> 16) & 1u)) >> 16;
    return (unsigned short)u;
}

// ---------------- tile partition + one-time prep (merged launch) -----------
// Blocks [0,gP): radix-partition edges into per-TILE arena regions.
// Blocks [gP,..): feat fp32->bf16 cast + frag-packed weight image build.
__global__ __launch_bounds__(256) void part_prep_k(
    const int* __restrict__ src, const int* __restrict__ dst,
    int* __restrict__ ccur, int* __restrict__ arena, int E, int NBUCK, int gP,
    const float* __restrict__ feat, unsigned short* __restrict__ featbf,
    const float* __restrict__ W1, const float* __restrict__ W2,
    const float* __restrict__ W3, const float* __restrict__ W4,
    unsigned short* __restrict__ img, int n8)
{
    __shared__ int  histA[BINMAX];          // counts -> lcur (in place)
    __shared__ int  deltaA[BINMAX];         // global_base - block_excl
    __shared__ int  part[256];
    __shared__ int  stage[EPB];
    __shared__ unsigned short stageS[EPB];  // tile id per staged edge

    const int tid = threadIdx.x;

    if ((int)blockIdx.x >= gP) {
        // ---- prep path ----
        int i = ((int)blockIdx.x - gP) * 256 + tid;
        if (i < n8) {
            const float4* p = (const float4*)feat + (size_t)i * 2;
            float4 a = p[0], b = p[1];
            uint4 o;
            o.x = (unsigned)f2bf(a.x) | ((unsigned)f2bf(a.y) << 16);
            o.y = (unsigned)f2bf(a.z) | ((unsigned)f2bf(a.w) << 16);
            o.z = (unsigned)f2bf(b.x) | ((unsigned)f2bf(b.y) << 16);
            o.w = (unsigned)f2bf(b.z) | ((unsigned)f2bf(b.w) << 16);
            ((uint4*)featbf)[i] = o;
            return;
        }
        int t = i - n8;
        if (t >= WIMG_TOT) return;
        float v = 0.f;
        int s = t;
        if (s < W2F_OFF) {                       // W1 [64x64]
            int j = s & 7, m = (s >> 3) & 15, q = (s >> 7) & 3, kk = (s >> 9) & 1, c = s >> 10;
            v = W1[(kk * 32 + q * 8 + j) * 64 + c * 16 + m];
        } else if (s < W3F_OFF) {                // W2 [64x64]
            s -= W2F_OFF;
            int j = s & 7, m = (s >> 3) & 15, q = (s >> 7) & 3, kk = (s >> 9) & 1, c = s >> 10;
            v = W2[(kk * 32 + q * 8 + j) * 64 + c * 16 + m];
        } else if (s < W4F_OFF) {                // W3 [64x128]
            s -= W3F_OFF;
            int j = s & 7, m = (s >> 3) & 15, q = (s >> 7) & 3, kk = (s >> 9) & 1, c = s >> 10;
            v = W3[(kk * 32 + q * 8 + j) * 128 + c * 16 + m];
        } else {                                 // W4 [128x40], cols padded 48
            s -= W4F_OFF;
            int j = s & 7, m = (s >> 3) & 15, q = (s >> 7) & 3, kk = (s >> 9) & 3, c = s >> 11;
            int n = c * 16 + m;
            if (n < 40) v = W4[(kk * 32 + q * 8 + j) * 40 + n];
        }
        img[t] = f2bf(v);
        return;
    }

    // ---- partition path ----
    const int e0  = blockIdx.x * EPB;
    const int ec  = min(EPB, E - e0);

    int pk[EPT], bk[EPT];
    for (int k = tid; k < BINMAX; k += 256) histA[k] = 0;
    __syncthreads();
    #pragma unroll
    for (int j = 0; j < EPT; j++) {
        int idx = tid + j * 256;
        if (idx < ec) {
            int s = src[e0 + idx];
            int d = dst[e0 + idx];
            bk[j] = d >> TSHIFT;                 // tile id (0..1562)
            pk[j] = s | ((d & 63) << 17);        // src 17b | fine-node 6b
            atomicAdd(&histA[bk[j]], 1);
        } else bk[j] = -1;
    }
    __syncthreads();
    // 7-bins-per-thread local sums -> 256-wide scan -> per-bin offsets
    int loc[BPT];
    int ssum = 0;
    #pragma unroll
    for (int k = 0; k < BPT; k++) {
        loc[k] = ssum;
        ssum += histA[tid * BPT + k];
    }
    part[tid] = ssum;
    __syncthreads();
    for (int dd = 1; dd < 256; dd <<= 1) {
        int v = 0;
        if (tid >= dd) v = part[tid - dd];
        __syncthreads();
        if (tid >= dd) part[tid] += v;
        __syncthreads();
    }
    const int base0 = part[tid] - ssum;
    #pragma unroll
    for (int k = 0; k < BPT; k++) {
        int b  = tid * BPT + k;
        int h  = histA[b];
        int ex = base0 + loc[k];
        int gb = 0;
        if (b < NBUCK && h > 0) gb = atomicAdd(ccur + b, h);
        deltaA[b] = gb - ex;
        histA[b]  = ex;                          // becomes lcur
    }
    __syncthreads();
    #pragma unroll
    for (int j = 0; j < EPT; j++) {
        if (bk[j] >= 0) {
            int l = atomicAdd(&histA[bk[j]], 1);
            stage[l]  = pk[j];
            stageS[l] = (unsigned short)bk[j];
        }
    }
    __syncthreads();
    for (int i = tid; i < ec; i += 256) {
        int b = stageS[i];
        arena[(size_t)b * CAP + i + deltaA[b]] = stage[i];
    }
}

// ---------------- in-block fine sort + wave-local register gather ----------
// Phase A: 64-bin int histogram (native ds_add) + 64-lane shuffle scan +
//   LDS scatter of 17-bit src ids -> sortedE grouped by fine node.
// Phase B: R13-proven register gather: 8 lanes/row, 8-deep load batching,
//   fp32 register accumulate, mean via v_rcp, bf16 pack into Agg (own rows).
#define ACC8(v)                                    \
    acc[0] += __uint_as_float((v).x << 16);        \
    acc[1] += __uint_as_float((v).x & 0xFFFF0000u);\
    acc[2] += __uint_as_float((v).y << 16);        \
    acc[3] += __uint_as_float((v).y & 0xFFFF0000u);\
    acc[4] += __uint_as_float((v).z << 16);        \
    acc[5] += __uint_as_float((v).z & 0xFFFF0000u);\
    acc[6] += __uint_as_float((v).w << 16);        \
    acc[7] += __uint_as_float((v).w & 0xFFFF0000u);

__device__ __forceinline__ void gather_tile_sorted(
    const unsigned short* __restrict__ h, const int* __restrict__ ebase,
    int ec, int* __restrict__ sortedE, int* __restrict__ cnt,
    int* __restrict__ beg, int* __restrict__ cur,
    unsigned short* __restrict__ Agg, int rowB, int N, int tid)
{
    ec = min(ec, CAP);
    if (tid < 64) cnt[tid] = 0;
    __syncthreads();

    int pk[8];                                   // static-indexed (rule #20)
    #pragma unroll
    for (int j = 0; j < 8; j++) {
        int idx = tid + j * 256;
        pk[j] = (idx < ec) ? ebase[idx] : -1;
        if (pk[j] >= 0) atomicAdd(&cnt[(pk[j] >> 17) & 63], 1);
    }
    __syncthreads();

    if (tid < 64) {                              // wave-0 shuffle scan
        int c = cnt[tid];
        int v = c;
        #pragma unroll
        for (int d = 1; d < 64; d <<= 1) {
            int t = __shfl_up(v, d);
            if (tid >= d) v += t;
        }
        beg[tid] = v - c;
        cur[tid] = v - c;
    }
    __syncthreads();

    #pragma unroll
    for (int j = 0; j < 8; j++) {
        if (pk[j] >= 0) {
            int pos = atomicAdd(&cur[(pk[j] >> 17) & 63], 1);
            sortedE[pos] = pk[j] & 0x1FFFF;
        }
    }
    __syncthreads();

    const int w = tid >> 6, lane = tid & 63;
    #pragma unroll
    for (int pass = 0; pass < 2; pass++) {
        int rl = w * 16 + pass * 8 + (lane >> 3);
        int g  = rowB + rl;
        int q  = (lane & 7) * 8;
        uint4 p = make_uint4(0u, 0u, 0u, 0u);
        if (g < N) {
            int bgi = beg[rl];
            int end = bgi + cnt[rl];
            float acc[8] = {0.f, 0.f, 0.f, 0.f, 0.f, 0.f, 0.f, 0.f};
            int i = bgi;
            for (; i + 8 <= end; i += 8) {       // 8 loads in flight per lane
                int s0 = sortedE[i],     s1 = sortedE[i + 1];
                int s2 = sortedE[i + 2], s3 = sortedE[i + 3];
                int s4 = sortedE[i + 4], s5 = sortedE[i + 5];
                int s6 = sortedE[i + 6], s7 = sortedE[i + 7];
                uint4 v0 = *(const uint4*)(h + (size_t)s0 * 64 + q);
                uint4 v1 = *(const uint4*)(h + (size_t)s1 * 64 + q);
                uint4 v2 = *(const uint4*)(h + (size_t)s2 * 64 + q);
                uint4 v3 = *(const uint4*)(h + (size_t)s3 * 64 + q);
                uint4 v4 = *(const uint4*)(h + (size_t)s4 * 64 + q);
                uint4 v5 = *(const uint4*)(h + (size_t)s5 * 64 + q);
                uint4 v6 = *(const uint4*)(h + (size_t)s6 * 64 + q);
                uint4 v7 = *(const uint4*)(h + (size_t)s7 * 64 + q);
                ACC8(v0); ACC8(v1); ACC8(v2); ACC8(v3);
                ACC8(v4); ACC8(v5); ACC8(v6); ACC8(v7);
            }
            for (; i + 2 <= end; i += 2) {
                int s0 = sortedE[i], s1 = sortedE[i + 1];
                uint4 v0 = *(const uint4*)(h + (size_t)s0 * 64 + q);
                uint4 v1 = *(const uint4*)(h + (size_t)s1 * 64 + q);
                ACC8(v0); ACC8(v1);
            }
            for (; i < end; i++) {
                uint4 v = *(const uint4*)(h + (size_t)sortedE[i] * 64 + q);
                ACC8(v);
            }
            // v_rcp_f32: 2^-22 rel err, absorbed by the bf16 round
            float inv = __builtin_amdgcn_rcpf((float)max(end - bgi, 1));
            p.x = (unsigned)f2bf(acc[0]*inv) | ((unsigned)f2bf(acc[1]*inv) << 16);
            p.y = (unsigned)f2bf(acc[2]*inv) | ((unsigned)f2bf(acc[3]*inv) << 16);
            p.z = (unsigned)f2bf(acc[4]*inv) | ((unsigned)f2bf(acc[5]*inv) << 16);
            p.w = (unsigned)f2bf(acc[6]*inv) | ((unsigned)f2bf(acc[7]*inv) << 16);
        }
        *(uint4*)(Agg + rl * 72 + q) = p;
    }
}

// ---------------- fused sort + gather + GEMM1 + sigmoid -> t1 --------------
__global__ __launch_bounds__(256) void aggemm1_k(
    const unsigned short* __restrict__ featbf, const int* __restrict__ ccur,
    const int* __restrict__ arena, const unsigned short* __restrict__ img,
    const float* __restrict__ bias, unsigned short* __restrict__ t1, int N)
{
    __shared__ alignas(16) unsigned char SMEM[SMEM_BYTES];
    int*            sortedE = (int*)SMEM;
    unsigned short* Agg     = (unsigned short*)(SMEM + 9216);
    int*            cnt     = (int*)(SMEM + 18432);
    int*            beg     = (int*)(SMEM + 18688);
    int*            cur     = (int*)(SMEM + 18944);

    const int tid = threadIdx.x;
    const int tile = blockIdx.x;
    const int rowB = tile * 64;
    const int w = tid >> 6, lane = tid & 63;
    const int m = lane & 15, quad = lane >> 4;
    const int row0 = rowB + w * 16;

    gather_tile_sorted(featbf, arena + (size_t)tile * CAP, ccur[tile],
                       sortedE, cnt, beg, cur, Agg, rowB, N, tid);

    const short8* Wf = (const short8*)(img + W1F_OFF);
    floatx4 acc[4];
    #pragma unroll
    for (int c = 0; c < 4; c++) acc[c] = (floatx4){0.f, 0.f, 0.f, 0.f};
    #pragma unroll
    for (int kk = 0; kk < 2; kk++) {
        short8 a = *(const short8*)(Agg + (w * 16 + m) * 72 + kk * 32 + quad * 8);
        #pragma unroll
        for (int c = 0; c < 4; c++) {
            short8 b = Wf[((c * 2 + kk) * 4 + quad) * 16 + m];
            acc[c] = __builtin_amdgcn_mfma_f32_16x16x32_bf16(a, b, acc[c], 0, 0, 0);
        }
    }
    bool dzr[4];
    int rows[4];
    #pragma unroll
    for (int r = 0; r < 4; r++) {
        rows[r] = row0 + quad * 4 + r;
        dzr[r] = (cnt[w * 16 + quad * 4 + r] == 0);
    }
    #pragma unroll
    for (int c = 0; c < 4; c++) {
        int col = c * 16 + m;
        float bv = bias[col];
        #pragma unroll
        for (int r = 0; r < 4; r++) {
            if (rows[r] < N) {
                float v = dzr[r] ? 0.5f : sigmoidf(acc[c][r] + bv);
                t1[(size_t)rows[r] * 64 + col] = f2bf(v);
            }
        }
    }
}

// ---------------- fused sort + gather + triple-GEMM -> out -----------------
// T2 aliases sortedE (dead after gather) -> one barrier after the gather.
__global__ __launch_bounds__(256) void aggep3_k(
    const unsigned short* __restrict__ t1, const int* __restrict__ ccur,
    const int* __restrict__ arena, const unsigned short* __restrict__ img,
    const float* __restrict__ b2, const float* __restrict__ b3,
    const float* __restrict__ b4, float* __restrict__ out, int N)
{
    __shared__ alignas(16) unsigned char SMEM[SMEM_BYTES];
    int*            sortedE = (int*)SMEM;
    unsigned short* T2      = (unsigned short*)SMEM;           // alias
    unsigned short* Agg     = (unsigned short*)(SMEM + 9216);
    unsigned short* H3h     = Agg;                             // alias
    int*            cnt     = (int*)(SMEM + 18432);
    int*            beg     = (int*)(SMEM + 18688);
    int*            cur     = (int*)(SMEM + 18944);

    const int tid = threadIdx.x;
    const int tile = blockIdx.x;
    const int rowB = tile * 64;
    const int w = tid >> 6, lane = tid & 63;
    const int m = lane & 15, quad = lane >> 4;
    const int row0 = rowB + w * 16;

    gather_tile_sorted(t1, arena + (size_t)tile * CAP, ccur[tile],
                       sortedE, cnt, beg, cur, Agg, rowB, N, tid);
    __syncthreads();    // all sortedE reads done before T2 (alias) writes

    // ---- phase 0: T2 = sigmoid(Agg @ W2 + b2) ----
    {
        const short8* Wf = (const short8*)(img + W2F_OFF);
        floatx4 acc[4];
        #pragma unroll
        for (int c = 0; c < 4; c++) acc[c] = (floatx4){0.f, 0.f, 0.f, 0.f};
        #pragma unroll
        for (int kk = 0; kk < 2; kk++) {
            short8 a = *(const short8*)(Agg + (w * 16 + m) * 72 + kk * 32 + quad * 8);
            #pragma unroll
            for (int c = 0; c < 4; c++) {
                short8 b = Wf[((c * 2 + kk) * 4 + quad) * 16 + m];
                acc[c] = __builtin_amdgcn_mfma_f32_16x16x32_bf16(a, b, acc[c], 0, 0, 0);
            }
        }
        bool dzr[4];
        #pragma unroll
        for (int r = 0; r < 4; r++)
            dzr[r] = (cnt[w * 16 + quad * 4 + r] == 0);
        #pragma unroll
        for (int c = 0; c < 4; c++) {
            int col = c * 16 + m;
            float bv = b2[col];
            #pragma unroll
            for (int r = 0; r < 4; r++) {
                int rl = w * 16 + quad * 4 + r;
                float v = dzr[r] ? 0.5f : sigmoidf(acc[c][r] + bv);
                T2[rl * 72 + col] = f2bf(v);
            }
        }
    }

    // ---- phases 1&2 split-K: per half, H3h = relu(T2@W3half+b3half),
    //      then acc2 += H3h @ W4[khalf] ----
    floatx4 acc2[3];
    #pragma unroll
    for (int c = 0; c < 3; c++) acc2[c] = (floatx4){0.f, 0.f, 0.f, 0.f};
    const short8* Wf3 = (const short8*)(img + W3F_OFF);
    const short8* Wf4 = (const short8*)(img + W4F_OFF);

    #pragma unroll
    for (int half = 0; half < 2; half++) {
        floatx4 acc[4];
        #pragma unroll
        for (int c = 0; c < 4; c++) acc[c] = (floatx4){0.f, 0.f, 0.f, 0.f};
        #pragma unroll
        for (int kk = 0; kk < 2; kk++) {
            short8 a = *(const short8*)(T2 + (w * 16 + m) * 72 + kk * 32 + quad * 8);
            #pragma unroll
            for (int c = 0; c < 4; c++) {
                short8 b = Wf3[(((half * 4 + c) * 2 + kk) * 4 + quad) * 16 + m];
                acc[c] = __builtin_amdgcn_mfma_f32_16x16x32_bf16(a, b, acc[c], 0, 0, 0);
            }
        }
        #pragma unroll
        for (int c = 0; c < 4; c++) {
            int col = c * 16 + m;
            float bv = b3[half * 64 + col];
            #pragma unroll
            for (int r = 0; r < 4; r++) {
                int rl = w * 16 + quad * 4 + r;
                H3h[rl * 72 + col] = f2bf(fmaxf(acc[c][r] + bv, 0.f));
            }
        }
        #pragma unroll
        for (int kk2 = 0; kk2 < 2; kk2++) {
            short8 a = *(const short8*)(H3h + (w * 16 + m) * 72 + kk2 * 32 + quad * 8);
            #pragma unroll
            for (int c = 0; c < 3; c++) {
                short8 b = Wf4[((c * 4 + half * 2 + kk2) * 4 + quad) * 16 + m];
                acc2[c] = __builtin_amdgcn_mfma_f32_16x16x32_bf16(a, b, acc2[c], 0, 0, 0);
            }
        }
    }

    // ---- store out = acc2 + b4 ----
    #pragma unroll
    for (int c = 0; c < 3; c++) {
        int col = c * 16 + m;
        if (col < 40) {
            float bv = b4[col];
            #pragma unroll
            for (int r = 0; r < 4; r++) {
                int row = row0 + quad * 4 + r;
                if (row < N) out[(size_t)row * 40 + col] = acc2[c][r] + bv;
            }
        }
    }
}

extern "C" void kernel_launch(void* const* d_in, const int* in_sizes, int n_in,
                              void* d_out, int out_size, void* d_ws, size_t ws_size,
                              hipStream_t stream)
{
    const float* feat = (const float*)d_in[0];
    const int*   eidx = (const int*)d_in[1];
    const float* W1 = (const float*)d_in[2];
    const float* b1 = (const float*)d_in[3];
    const float* W2 = (const float*)d_in[4];
    const float* b2 = (const float*)d_in[5];
    const float* W3 = (const float*)d_in[6];
    const float* b3 = (const float*)d_in[7];
    const float* W4 = (const float*)d_in[8];
    const float* b4 = (const float*)d_in[9];

    const int N = in_sizes[0] / 64;
    const int E = in_sizes[1] / 2;
    const int* src = eidx;
    const int* dst = eidx + E;

    const int NBUCK = (N + 63) >> TSHIFT;          // 1563 tiles

    unsigned short* featbf = (unsigned short*)d_ws;            // N*64 bf16
    unsigned short* t1     = featbf + (size_t)N * 64;          // N*64 bf16
    unsigned short* img    = t1     + (size_t)N * 64;          // WIMG_TOT
    int*   ccur  = (int*)(img + WIMG_TOT);                     // NBUCK
    int*   arena = ccur + NBUCK;                               // NBUCK*CAP
    float* out   = (float*)d_out;

    hipMemsetAsync(ccur, 0, (size_t)NBUCK * sizeof(int), stream);

    const dim3 blk(256);
    const int gP  = (E + EPB - 1) / EPB;
    const int g64 = (N + 63) / 64;                 // == NBUCK
    const int n8  = N * 64 / 8;
    const int gPC = (n8 + WIMG_TOT + 255) / 256;

    // tile-granular partition + prep (merged); csr_fine eliminated (R15/16)
    part_prep_k<<<gP + gPC, blk, 0, stream>>>(src, dst, ccur, arena, E, NBUCK,
                                              gP, feat, featbf, W1, W2, W3, W4,
                                              img, n8);

    // t1 = sigmoid(mean(featbf[src]) @ W1 + b1)
    aggemm1_k<<<g64, blk, 0, stream>>>(featbf, ccur, arena, img, b1, t1, N);
    // out = relu(sigmoid(mean(t1[src])@W2+b2)@W3+b3)@W4 + b4
    aggep3_k<<<g64, blk, 0, stream>>>(t1, ccur, arena, img, b2, b3, b4, out, N);
}

// Round 4
// 219.142 us; speedup vs baseline: 6.1902x; 1.0974x over previous
//
#include <hip/hip_runtime.h>

// HGCN on MI355X. logmap0(expmap0(v)) == v here, so the model reduces to:
//   t1 = sigmoid(segmean(feat@W1+b1)); t2 = sigmoid(segmean(t1@W2+b2))
//   out = relu(t2@W3+b3)@W4 + b4     (segmean commutes with the linear map;
//   deg-0 nodes: segmean = 0 -> value 0.5 exactly, handled via dz check)
// R1-R13: see session journal (atomic wall -> CSR; coarse buckets; bf16
//   gather rows; frag-packed weight image; wave-local zero-barrier MLP).
// R14: baseline re-anchor, 229.4us. aggep3 59us @ MfmaUtil 2%, VALUBusy 26%,
//   HBM 21% -> gathers latency-bound; part_prep+csr_fine ~110us.
// R15: FAILED (1356us). LDS float atomicAdd = CAS loop, not ds_add_f32.
// R16: FAILED (240us). Tile-granular partition: 1563 buckets shrank arena
//   scatter runs to 10.5B -> write-allocate amp (WRITE 45MB vs 19MB logical),
//   part_prep 70us; in-block sort cost ~10us per gather kernel (paid twice).
//   Lessons: partition needs COARSE buckets; sort once, not per-layer.
// R17: keep R14 partition EXACTLY (CSHIFT=9, 84B runs). Fix csr_fine where
//   the wall is: 1024 threads/block (16 waves) -> 4x less serial work, 4x
//   latency hiding. Split gather/GEMM kernels into 128-thread/32-row blocks
//   (wave-local pipeline needs nothing bigger): grid 3125, ~24 waves/CU vs
//   ~10 -> 2x latency hiding on the L2/L3-bound gather. Predicted ~160us.

constexpr int CSHIFT = 9;               // 512 nodes per coarse bucket
constexpr int CNODES = 1 << CSHIFT;
constexpr int EPB    = 4096;            // edges per partition block
constexpr int EPT    = EPB / 256;
constexpr int CAP    = 16384;           // arena capacity per bucket (mean 8163)

// frag-packed bf16 weight image (shorts). Fragment = 16 lanes x 8 shorts =
// 128 shorts; flat idx = (((c*KK + kk)*4 + quad)*16 + m)*8 + j.
constexpr int W1F_OFF = 0;              // 4x2x4 frags  = 4096 shorts
constexpr int W2F_OFF = 4096;           // 4096
constexpr int W3F_OFF = 8192;           // 8x2x4 frags  = 8192
constexpr int W4F_OFF = 16384;          // 3x4x4 frags  = 6144 (cols padded 48)
constexpr int WIMG_TOT = 22528;

typedef __attribute__((ext_vector_type(8))) short short8;   // 8 bf16
typedef __attribute__((ext_vector_type(4))) float floatx4;  // MFMA acc

__device__ __forceinline__ float sigmoidf(float x) {
    return 1.0f / (1.0f + __expf(-x));
}
__device__ __forceinline__ unsigned short f2bf(float f) {   // RNE f32->bf16
    unsigned int u = __float_as_uint(f);
    u = (u + 0x7FFFu + ((u >> 16) & 1u)) >> 16;
    return (unsigned short)u;
}

// ---------------- CSR partition + one-time prep (merged launch) ------------
// Blocks [0,gP): radix-partition edges into per-bucket arena regions.
// Blocks [gP,..): feat fp32->bf16 cast + frag-packed weight image build.
__global__ __launch_bounds__(256) void part_prep_k(
    const int* __restrict__ src, const int* __restrict__ dst,
    int* __restrict__ ccur, int* __restrict__ arena, int E, int NBUCK, int gP,
    const float* __restrict__ feat, unsigned short* __restrict__ featbf,
    const float* __restrict__ W1, const float* __restrict__ W2,
    const float* __restrict__ W3, const float* __restrict__ W4,
    unsigned short* __restrict__ img, int n8)
{
    __shared__ int  hist[256];
    __shared__ int  exoff[256];
    __shared__ int  lcur[256];
    __shared__ int  gbase[256];
    __shared__ int  stage[EPB];
    __shared__ unsigned char stageB[EPB];

    const int tid = threadIdx.x;

    if ((int)blockIdx.x >= gP) {
        // ---- prep path ----
        int i = ((int)blockIdx.x - gP) * 256 + tid;
        if (i < n8) {
            const float4* p = (const float4*)feat + (size_t)i * 2;
            float4 a = p[0], b = p[1];
            uint4 o;
            o.x = (unsigned)f2bf(a.x) | ((unsigned)f2bf(a.y) << 16);
            o.y = (unsigned)f2bf(a.z) | ((unsigned)f2bf(a.w) << 16);
            o.z = (unsigned)f2bf(b.x) | ((unsigned)f2bf(b.y) << 16);
            o.w = (unsigned)f2bf(b.z) | ((unsigned)f2bf(b.w) << 16);
            ((uint4*)featbf)[i] = o;
            return;
        }
        int t = i - n8;
        if (t >= WIMG_TOT) return;
        float v = 0.f;
        int s = t;
        if (s < W2F_OFF) {                       // W1 [64x64]
            int j = s & 7, m = (s >> 3) & 15, q = (s >> 7) & 3, kk = (s >> 9) & 1, c = s >> 10;
            v = W1[(kk * 32 + q * 8 + j) * 64 + c * 16 + m];
        } else if (s < W3F_OFF) {                // W2 [64x64]
            s -= W2F_OFF;
            int j = s & 7, m = (s >> 3) & 15, q = (s >> 7) & 3, kk = (s >> 9) & 1, c = s >> 10;
            v = W2[(kk * 32 + q * 8 + j) * 64 + c * 16 + m];
        } else if (s < W4F_OFF) {                // W3 [64x128]
            s -= W3F_OFF;
            int j = s & 7, m = (s >> 3) & 15, q = (s >> 7) & 3, kk = (s >> 9) & 1, c = s >> 10;
            v = W3[(kk * 32 + q * 8 + j) * 128 + c * 16 + m];
        } else {                                 // W4 [128x40], cols padded 48
            s -= W4F_OFF;
            int j = s & 7, m = (s >> 3) & 15, q = (s >> 7) & 3, kk = (s >> 9) & 3, c = s >> 11;
            int n = c * 16 + m;
            if (n < 40) v = W4[(kk * 32 + q * 8 + j) * 40 + n];
        }
        img[t] = f2bf(v);
        return;
    }

    // ---- partition path ----
    const int e0  = blockIdx.x * EPB;
    const int ec  = min(EPB, E - e0);

    int pk[EPT], bk[EPT];
    hist[tid] = 0;
    __syncthreads();
    #pragma unroll
    for (int j = 0; j < EPT; j++) {
        int idx = tid + j * 256;
        if (idx < ec) {
            int s = src[e0 + idx];
            int d = dst[e0 + idx];
            bk[j] = d >> CSHIFT;
            pk[j] = s | ((d & (CNODES - 1)) << 17);
            atomicAdd(&hist[bk[j]], 1);
        } else bk[j] = -1;
    }
    __syncthreads();
    const int h = hist[tid];
    exoff[tid] = h;
    __syncthreads();
    for (int dd = 1; dd < 256; dd <<= 1) {
        int v = 0;
        if (tid >= dd) v = exoff[tid - dd];
        __syncthreads();
        if (tid >= dd) exoff[tid] += v;
        __syncthreads();
    }
    const int ex = exoff[tid] - h;
    int gb = 0;
    if (tid < NBUCK && h > 0) gb = atomicAdd(ccur + tid, h);
    __syncthreads();
    exoff[tid] = ex;
    lcur[tid]  = ex;
    gbase[tid] = gb;
    __syncthreads();
    #pragma unroll
    for (int j = 0; j < EPT; j++) {
        if (bk[j] >= 0) {
            int l = atomicAdd(&lcur[bk[j]], 1);
            stage[l]  = pk[j];
            stageB[l] = (unsigned char)bk[j];
        }
    }
    __syncthreads();
    for (int i = tid; i < ec; i += 256) {
        int b = stageB[i];
        arena[(size_t)b * CAP + gbase[b] + (i - exoff[b])] = stage[i];
    }
}

// One 1024-thread block per coarse bucket (R17): 16 waves hide the arena
// read + LDS-atomic latency; inline scan of bucket counts -> cbeg; LDS
// counting sort over 512 nodes -> off/ssrc.
__global__ __launch_bounds__(1024) void csr_fine(const int* __restrict__ arena,
                                                 const int* __restrict__ ccur,
                                                 int* __restrict__ off,
                                                 int* __restrict__ ssrc,
                                                 int N, int E, int NBUCK) {
    __shared__ int part[256];
    __shared__ int cnt[CNODES];
    __shared__ int cur[CNODES];
    __shared__ int wpre[8];
    const int b = blockIdx.x;
    const int node0 = b << CSHIFT;
    const int tid = threadIdx.x;
    const int lane = tid & 63, wid = tid >> 6;

    // exclusive prefix of ccur over buckets -> cbeg (threads 0-255 work,
    // ALL threads hit every barrier)
    if (tid < 256) part[tid] = (tid < NBUCK) ? ccur[tid] : 0;
    __syncthreads();
    for (int d = 1; d < 256; d <<= 1) {
        int v = 0;
        if (tid < 256 && tid >= d) v = part[tid - d];
        __syncthreads();
        if (tid < 256 && tid >= d) part[tid] += v;
        __syncthreads();
    }
    const int cbeg = (b > 0) ? part[b - 1] : 0;
    const int ec   = min(ccur[b], CAP);
    if (b == 0 && tid == 0) off[N] = E;

    if (tid < CNODES) cnt[tid] = 0;
    __syncthreads();
    const int* pe = arena + (size_t)b * CAP;
    for (int i = tid; i < ec; i += 1024)
        atomicAdd(&cnt[(pe[i] >> 17) & (CNODES - 1)], 1);
    __syncthreads();

    // hierarchical scan of cnt[512]: shuffle within 8 waves + serial wave scan
    int c = (tid < CNODES) ? cnt[tid] : 0;
    int v = c;
    #pragma unroll
    for (int d = 1; d < 64; d <<= 1) {
        int t = __shfl_up(v, d);
        if (lane >= d) v += t;
    }
    if (tid < CNODES && lane == 63) wpre[wid] = v;
    __syncthreads();
    if (tid == 0) {
        int s = 0;
        #pragma unroll
        for (int k = 0; k < CNODES / 64; k++) { int t = wpre[k]; wpre[k] = s; s += t; }
    }
    __syncthreads();
    if (tid < CNODES) {
        int ex = wpre[wid] + v - c;              // exclusive prefix in bucket
        cur[tid] = ex;
        int node = node0 + tid;
        if (node < N) off[node] = cbeg + ex;
    }
    __syncthreads();
    for (int i = tid; i < ec; i += 1024) {
        int p = pe[i];
        int pos = cbeg + atomicAdd(&cur[(p >> 17) & (CNODES - 1)], 1);
        ssrc[pos] = p & 0x1FFFF;
    }
}

// ---------------- wave-local gather: mean of h[src] rows into LDS tile -----
// Wave w gathers ITS OWN rows w*16..w*16+15 (2 passes x 8 rows x 8 lanes).
// All later reads of Agg by wave w hit only these rows -> no barrier needed.
#define ACC8(v)                                    \
    acc[0] += __uint_as_float((v).x << 16);        \
    acc[1] += __uint_as_float((v).x & 0xFFFF0000u);\
    acc[2] += __uint_as_float((v).y << 16);        \
    acc[3] += __uint_as_float((v).y & 0xFFFF0000u);\
    acc[4] += __uint_as_float((v).z << 16);        \
    acc[5] += __uint_as_float((v).z & 0xFFFF0000u);\
    acc[6] += __uint_as_float((v).w << 16);        \
    acc[7] += __uint_as_float((v).w & 0xFFFF0000u);

__device__ __forceinline__ void gather_tile_wave(
    const unsigned short* __restrict__ h, const int* __restrict__ off,
    const int* __restrict__ ssrc, unsigned short* Agg, int rowB, int N,
    int w, int lane)
{
    #pragma unroll
    for (int pass = 0; pass < 2; pass++) {
        int rl = w * 16 + pass * 8 + (lane >> 3);
        int g  = rowB + rl;
        int q  = (lane & 7) * 8;
        uint4 p = make_uint4(0u, 0u, 0u, 0u);
        if (g < N) {
            int beg = off[g], end = off[g + 1];
            float acc[8] = {0.f, 0.f, 0.f, 0.f, 0.f, 0.f, 0.f, 0.f};
            int i = beg;
            for (; i + 8 <= end; i += 8) {       // 8 loads in flight per lane
                uint4 v0 = *(const uint4*)(h + (size_t)ssrc[i]     * 64 + q);
                uint4 v1 = *(const uint4*)(h + (size_t)ssrc[i + 1] * 64 + q);
                uint4 v2 = *(const uint4*)(h + (size_t)ssrc[i + 2] * 64 + q);
                uint4 v3 = *(const uint4*)(h + (size_t)ssrc[i + 3] * 64 + q);
                uint4 v4 = *(const uint4*)(h + (size_t)ssrc[i + 4] * 64 + q);
                uint4 v5 = *(const uint4*)(h + (size_t)ssrc[i + 5] * 64 + q);
                uint4 v6 = *(const uint4*)(h + (size_t)ssrc[i + 6] * 64 + q);
                uint4 v7 = *(const uint4*)(h + (size_t)ssrc[i + 7] * 64 + q);
                ACC8(v0); ACC8(v1); ACC8(v2); ACC8(v3);
                ACC8(v4); ACC8(v5); ACC8(v6); ACC8(v7);
            }
            for (; i + 2 <= end; i += 2) {
                uint4 v0 = *(const uint4*)(h + (size_t)ssrc[i]     * 64 + q);
                uint4 v1 = *(const uint4*)(h + (size_t)ssrc[i + 1] * 64 + q);
                ACC8(v0); ACC8(v1);
            }
            for (; i < end; i++) {
                uint4 v = *(const uint4*)(h + (size_t)ssrc[i] * 64 + q);
                ACC8(v);
            }
            // v_rcp_f32: 2^-22 rel err, absorbed by the bf16 round
            float inv = __builtin_amdgcn_rcpf((float)max(end - beg, 1));
            p.x = (unsigned)f2bf(acc[0]*inv) | ((unsigned)f2bf(acc[1]*inv) << 16);
            p.y = (unsigned)f2bf(acc[2]*inv) | ((unsigned)f2bf(acc[3]*inv) << 16);
            p.z = (unsigned)f2bf(acc[4]*inv) | ((unsigned)f2bf(acc[5]*inv) << 16);
            p.w = (unsigned)f2bf(acc[6]*inv) | ((unsigned)f2bf(acc[7]*inv) << 16);
        }
        *(uint4*)(Agg + rl * 72 + q) = p;
    }
}

// ---------------- fused gather + GEMM1 + sigmoid -> t1 ---------------------
// R17: 128 threads / 32-row tile, grid 3125 -> ~24 waves/CU latency hiding.
__global__ __launch_bounds__(128) void aggemm1_k(
    const unsigned short* __restrict__ featbf, const int* __restrict__ off,
    const int* __restrict__ ssrc, const unsigned short* __restrict__ img,
    const float* __restrict__ bias, unsigned short* __restrict__ t1, int N)
{
    __shared__ alignas(16) unsigned short Agg[32 * 72];   // 4.6 KB

    const int tid = threadIdx.x;
    const int rowB = blockIdx.x * 32;
    const int w = tid >> 6, lane = tid & 63;
    const int m = lane & 15, quad = lane >> 4;
    const int row0 = rowB + w * 16;

    gather_tile_wave(featbf, off, ssrc, Agg, rowB, N, w, lane);

    const short8* Wf = (const short8*)(img + W1F_OFF);
    floatx4 acc[4];
    #pragma unroll
    for (int c = 0; c < 4; c++) acc[c] = (floatx4){0.f, 0.f, 0.f, 0.f};
    #pragma unroll
    for (int kk = 0; kk < 2; kk++) {
        short8 a = *(const short8*)(Agg + (w * 16 + m) * 72 + kk * 32 + quad * 8);
        #pragma unroll
        for (int c = 0; c < 4; c++) {
            short8 b = Wf[((c * 2 + kk) * 4 + quad) * 16 + m];
            acc[c] = __builtin_amdgcn_mfma_f32_16x16x32_bf16(a, b, acc[c], 0, 0, 0);
        }
    }
    bool dzr[4];
    int rows[4];
    #pragma unroll
    for (int r = 0; r < 4; r++) {
        rows[r] = row0 + quad * 4 + r;
        dzr[r] = (rows[r] < N) ? (off[rows[r] + 1] == off[rows[r]]) : false;
    }
    #pragma unroll
    for (int c = 0; c < 4; c++) {
        int col = c * 16 + m;
        float bv = bias[col];
        #pragma unroll
        for (int r = 0; r < 4; r++) {
            if (rows[r] < N) {
                float v = dzr[r] ? 0.5f : sigmoidf(acc[c][r] + bv);
                t1[(size_t)rows[r] * 64 + col] = f2bf(v);
            }
        }
    }
}

// ---------------- fused gather + triple-GEMM -> out ------------------------
// 128 threads / 32-row tile; LDS: T2[0,2304) | Agg/H3h[2304,4608) shorts.
// Every LDS row is touched only by its owning wave -> in-wave ordering
// (lgkmcnt) is sufficient, no __syncthreads anywhere.
__global__ __launch_bounds__(128) void aggep3_k(
    const unsigned short* __restrict__ t1, const int* __restrict__ off,
    const int* __restrict__ ssrc, const unsigned short* __restrict__ img,
    const float* __restrict__ b2, const float* __restrict__ b3,
    const float* __restrict__ b4, float* __restrict__ out, int N)
{
    __shared__ alignas(16) unsigned short SM[4608];   // 9.2 KB
    unsigned short* T2  = SM;            // 32 x 72
    unsigned short* Agg = SM + 2304;     // 32 x 72 (dead after phase 0)
    unsigned short* H3h = SM + 2304;     // 32 x 72 (aliases Agg)

    const int tid = threadIdx.x;
    const int rowB = blockIdx.x * 32;
    const int w = tid >> 6, lane = tid & 63;
    const int m = lane & 15, quad = lane >> 4;
    const int row0 = rowB + w * 16;

    gather_tile_wave(t1, off, ssrc, Agg, rowB, N, w, lane);

    // ---- phase 0: T2 = sigmoid(Agg @ W2 + b2) ----
    {
        const short8* Wf = (const short8*)(img + W2F_OFF);
        floatx4 acc[4];
        #pragma unroll
        for (int c = 0; c < 4; c++) acc[c] = (floatx4){0.f, 0.f, 0.f, 0.f};
        #pragma unroll
        for (int kk = 0; kk < 2; kk++) {
            short8 a = *(const short8*)(Agg + (w * 16 + m) * 72 + kk * 32 + quad * 8);
            #pragma unroll
            for (int c = 0; c < 4; c++) {
                short8 b = Wf[((c * 2 + kk) * 4 + quad) * 16 + m];
                acc[c] = __builtin_amdgcn_mfma_f32_16x16x32_bf16(a, b, acc[c], 0, 0, 0);
            }
        }
        bool dzr[4];
        #pragma unroll
        for (int r = 0; r < 4; r++) {
            int row = row0 + quad * 4 + r;
            dzr[r] = (row < N) ? (off[row + 1] == off[row]) : false;
        }
        #pragma unroll
        for (int c = 0; c < 4; c++) {
            int col = c * 16 + m;
            float bv = b2[col];
            #pragma unroll
            for (int r = 0; r < 4; r++) {
                int rl = w * 16 + quad * 4 + r;
                float v = dzr[r] ? 0.5f : sigmoidf(acc[c][r] + bv);
                T2[rl * 72 + col] = f2bf(v);
            }
        }
    }

    // ---- phases 1&2 split-K: per half, H3h = relu(T2@W3half+b3half),
    //      then acc2 += H3h @ W4[khalf] ----
    floatx4 acc2[3];
    #pragma unroll
    for (int c = 0; c < 3; c++) acc2[c] = (floatx4){0.f, 0.f, 0.f, 0.f};
    const short8* Wf3 = (const short8*)(img + W3F_OFF);
    const short8* Wf4 = (const short8*)(img + W4F_OFF);

    #pragma unroll
    for (int half = 0; half < 2; half++) {
        floatx4 acc[4];
        #pragma unroll
        for (int c = 0; c < 4; c++) acc[c] = (floatx4){0.f, 0.f, 0.f, 0.f};
        #pragma unroll
        for (int kk = 0; kk < 2; kk++) {
            short8 a = *(const short8*)(T2 + (w * 16 + m) * 72 + kk * 32 + quad * 8);
            #pragma unroll
            for (int c = 0; c < 4; c++) {
                short8 b = Wf3[(((half * 4 + c) * 2 + kk) * 4 + quad) * 16 + m];
                acc[c] = __builtin_amdgcn_mfma_f32_16x16x32_bf16(a, b, acc[c], 0, 0, 0);
            }
        }
        #pragma unroll
        for (int c = 0; c < 4; c++) {
            int col = c * 16 + m;
            float bv = b3[half * 64 + col];
            #pragma unroll
            for (int r = 0; r < 4; r++) {
                int rl = w * 16 + quad * 4 + r;
                H3h[rl * 72 + col] = f2bf(fmaxf(acc[c][r] + bv, 0.f));
            }
        }
        #pragma unroll
        for (int kk2 = 0; kk2 < 2; kk2++) {
            short8 a = *(const short8*)(H3h + (w * 16 + m) * 72 + kk2 * 32 + quad * 8);
            #pragma unroll
            for (int c = 0; c < 3; c++) {
                short8 b = Wf4[((c * 4 + half * 2 + kk2) * 4 + quad) * 16 + m];
                acc2[c] = __builtin_amdgcn_mfma_f32_16x16x32_bf16(a, b, acc2[c], 0, 0, 0);
            }
        }
    }

    // ---- store out = acc2 + b4 ----
    #pragma unroll
    for (int c = 0; c < 3; c++) {
        int col = c * 16 + m;
        if (col < 40) {
            float bv = b4[col];
            #pragma unroll
            for (int r = 0; r < 4; r++) {
                int row = row0 + quad * 4 + r;
                if (row < N) out[(size_t)row * 40 + col] = acc2[c][r] + bv;
            }
        }
    }
}

extern "C" void kernel_launch(void* const* d_in, const int* in_sizes, int n_in,
                              void* d_out, int out_size, void* d_ws, size_t ws_size,
                              hipStream_t stream)
{
    const float* feat = (const float*)d_in[0];
    const int*   eidx = (const int*)d_in[1];
    const float* W1 = (const float*)d_in[2];
    const float* b1 = (const float*)d_in[3];
    const float* W2 = (const float*)d_in[4];
    const float* b2 = (const float*)d_in[5];
    const float* W3 = (const float*)d_in[6];
    const float* b3 = (const float*)d_in[7];
    const float* W4 = (const float*)d_in[8];
    const float* b4 = (const float*)d_in[9];

    const int N = in_sizes[0] / 64;
    const int E = in_sizes[1] / 2;
    const int* src = eidx;
    const int* dst = eidx + E;

    const int NBUCK = (N + CNODES - 1) / CNODES;   // 196

    unsigned short* featbf = (unsigned short*)d_ws;            // N*64 bf16
    unsigned short* t1     = featbf + (size_t)N * 64;          // N*64 bf16
    unsigned short* img    = t1     + (size_t)N * 64;          // WIMG_TOT
    int*   off   = (int*)(img + WIMG_TOT);                     // N+1
    int*   ccur  = off + (N + 1);                              // NBUCK
    int*   ssrc  = ccur + NBUCK;                               // E
    int*   arena = ssrc + E;                                   // NBUCK*CAP
    float* out   = (float*)d_out;

    hipMemsetAsync(ccur, 0, (size_t)NBUCK * sizeof(int), stream);

    const dim3 blk(256);
    const int gP  = (E + EPB - 1) / EPB;
    const int g32 = (N + 31) / 32;
    const int n8  = N * 64 / 8;
    const int gPC = (n8 + WIMG_TOT + 255) / 256;

    // CSR partition + prep (merged), then per-bucket counting sort (16 waves)
    part_prep_k<<<gP + gPC, blk, 0, stream>>>(src, dst, ccur, arena, E, NBUCK,
                                              gP, feat, featbf, W1, W2, W3, W4,
                                              img, n8);
    csr_fine<<<NBUCK, dim3(1024), 0, stream>>>(arena, ccur, off, ssrc, N, E, NBUCK);

    // t1 = sigmoid(mean(featbf[src]) @ W1 + b1)   [fused, 0 barriers]
    aggemm1_k<<<g32, dim3(128), 0, stream>>>(featbf, off, ssrc, img, b1, t1, N);
    // out = relu(sigmoid(mean(t1[src])@W2+b2)@W3+b3)@W4 + b4  [fused, 0 barriers]
    aggep3_k<<<g32, dim3(128), 0, stream>>>(t1, off, ssrc, img, b2, b3, b4, out, N);
}